// Round 3
// baseline (95697.089 us; speedup 1.0000x reference)
//
#include <hip/hip_runtime.h>
#include <math.h>

typedef __attribute__((ext_vector_type(8))) short short8v;
typedef __attribute__((ext_vector_type(4))) float float4v;

#define BB 64
#define TT 1024
#define DD 128
#define HH 512

// ---- ws layout: ushort (bf16) region, element offsets ----
#define O_WHH_HI  0u         // [4 units][1536][512]
#define O_WHH_LO  3145728u
#define O_WIH1_HI 6291456u   // [2 dir][1536][512]
#define O_WIH1_LO 7864320u
#define O_WIH0_HI 9437184u   // [2 dir][1536][128]
#define O_WIH0_LO 9830400u
#define O_H0_HI   10223616u  // [2 dir][4 slot][64 b][512 j]
#define O_H0_LO   10485760u
#define O_H1_HI   10747904u  // [2 dir][2 slot][64 b][512 j]
#define O_H1_LO   10878976u
#define H_ZERO_N  786432u    // ushorts to zero from O_H0_HI
// ---- float region (ws as float*) ----
#define OF_FCIN   5505024u   // 131072 f
#define OF_FC1O   5636096u   //  65536 f
#define OF_FC2O   5701632u   //  32768 f
#define OI_FLAGS  5734400u   // 256 ints (as int* into float region)

#define DYN_LDS   67584      // [8][32][66] f32 reduction buffer

struct PP {
  const float* x;
  const float* bih[4];
  const float* bhh[4];
  unsigned short* wsu;
  int* flags;
};

__device__ __forceinline__ unsigned short bf16_rne(float f) {
  unsigned u = __builtin_bit_cast(unsigned, f);
  u += 0x7FFFu + ((u >> 16) & 1u);
  return (unsigned short)(u >> 16);
}
__device__ __forceinline__ float bf16_f(unsigned short h) {
  unsigned u = ((unsigned)h) << 16;
  return __builtin_bit_cast(float, u);
}
__device__ __forceinline__ float4v MF(short8v a, short8v b, float4v c) {
  return __builtin_amdgcn_mfma_f32_16x16x32_bf16(a, b, c, 0, 0, 0);
}
// row within stacked-[3*512] W for local row rl (0..31); -1 => zero frag
__device__ __forceinline__ int rowmap(int rl, int inp, int j0) {
  if (rl < 8)  return j0 + rl;
  if (rl < 16) return 512 + j0 + (rl - 8);
  if (rl < 24) return inp ? (1024 + j0 + rl - 16) : -1;
  return inp ? -1 : (1024 + j0 + rl - 24);
}
__device__ __forceinline__ short8v ldA(const unsigned short* W, int K, int row, int kofs) {
  return *(const short8v*)(W + (size_t)row * K + kofs);
}

// 256 blocks x 512 thr. u=bid>>6 (dir*2+layer), jt=bid&63 -> 8 j's.
// 8 waves split K; MFMA C[32 rows x 64 b]; rows: 0-7 r, 8-15 z, 16-23 n_ih, 24-31 n_hh.
__global__ __launch_bounds__(512) void gru_mfma(PP p) {
  extern __shared__ float red[];  // [8][32][66]
  const int bid = blockIdx.x;
  const int u = bid >> 6, dir = u >> 1, layer = u & 1;
  const int jt = bid & 63, j0 = jt * 8;
  const int tid = threadIdx.x, wid = tid >> 6, lane = tid & 63;
  const int lr = lane & 15, lq = lane >> 4;
  unsigned short* wsu = p.wsu;

  // ---- preload A fragments (weights) into VGPRs ----
  short8v Ah[2][4], Al[2][4];
  #pragma unroll
  for (int mt = 0; mt < 2; ++mt)
    #pragma unroll
    for (int i = 0; i < 4; ++i) { Ah[mt][i] = (short8v)0; Al[mt][i] = (short8v)0; }

  if (layer) {
    const int inp = (wid < 4);  // waves 0-3: input part (Wih_l1), 4-7: hidden (Whh)
    const unsigned short* Whi = inp ? (wsu + O_WIH1_HI + dir * 786432u)
                                    : (wsu + O_WHH_HI + (unsigned)u * 786432u);
    const unsigned short* Wlo = inp ? (wsu + O_WIH1_LO + dir * 786432u)
                                    : (wsu + O_WHH_LO + (unsigned)u * 786432u);
    #pragma unroll
    for (int i = 0; i < 4; ++i) {
      const int kst_m = (wid * 4 + i) - (inp ? 0 : 16);
      const int kofs = kst_m * 32 + lq * 8;
      #pragma unroll
      for (int mt = 0; mt < 2; ++mt) {
        const int row = rowmap(mt * 16 + lr, inp, j0);
        if (row >= 0) { Ah[mt][i] = ldA(Whi, 512, row, kofs); Al[mt][i] = ldA(Wlo, 512, row, kofs); }
      }
    }
  } else {
    const unsigned short* Whi = wsu + O_WHH_HI + (unsigned)u * 786432u;
    const unsigned short* Wlo = wsu + O_WHH_LO + (unsigned)u * 786432u;
    #pragma unroll
    for (int i = 0; i < 2; ++i) {
      const int kofs = (wid * 2 + i) * 32 + lq * 8;
      #pragma unroll
      for (int mt = 0; mt < 2; ++mt) {
        const int row = rowmap(mt * 16 + lr, 0, j0);
        if (row >= 0) { Ah[mt][i] = ldA(Whi, 512, row, kofs); Al[mt][i] = ldA(Wlo, 512, row, kofs); }
      }
    }
    if (wid < 4) {  // x part: K=128, wave wid owns kst wid
      const unsigned short* Xhi = wsu + O_WIH0_HI + dir * 196608u;
      const unsigned short* Xlo = wsu + O_WIH0_LO + dir * 196608u;
      const int kofs = wid * 32 + lq * 8;
      #pragma unroll
      for (int mt = 0; mt < 2; ++mt) {
        const int row = rowmap(mt * 16 + lr, 1, j0);
        if (row >= 0) { Ah[mt][2] = ldA(Xhi, 128, row, kofs); Al[mt][2] = ldA(Xlo, 128, row, kofs); }
      }
    }
  }

  // ---- biases (per gate-thread j) ----
  const int jth = tid >> 6, bth = tid & 63;  // gate stage: 8 j x 64 b
  const float br   = p.bih[u][j0 + jth] + p.bhh[u][j0 + jth];
  const float bz   = p.bih[u][512 + j0 + jth] + p.bhh[u][512 + j0 + jth];
  const float bnih = p.bih[u][1024 + j0 + jth];
  const float bnhh = p.bhh[u][1024 + j0 + jth];

  int* own = p.flags + u * 64;
  int* sib = p.flags + (layer ? (u - 1) : (u + 1)) * 64;
  const int sBeg = layer ? 1 : 0;
  const int sEnd = layer ? TT : (TT - 1);

  for (int s = sBeg; s <= sEnd; ++s) {
    // ---- wait for dependencies (wave 0 polls, monotonic flags) ----
    if (wid == 0) {
      const int T1 = s - 1;
      const int T2 = layer ? (s - 1) : (s - 3);
      int iter = 0; bool died = false;
      while (true) {
        int f1 = __hip_atomic_load(own + lane, __ATOMIC_RELAXED, __HIP_MEMORY_SCOPE_AGENT);
        int f2 = __hip_atomic_load(sib + lane, __ATOMIC_RELAXED, __HIP_MEMORY_SCOPE_AGENT);
        if (__all(f1 >= T1 && f2 >= T2)) break;
        if (++iter > 1000000) { died = true; break; }
        __builtin_amdgcn_s_sleep(2);
      }
      if (died && lane == 0)  // failsafe: release everyone, results will be wrong but terminate
        __hip_atomic_store(own + jt, 1 << 29, __ATOMIC_RELEASE, __HIP_MEMORY_SCOPE_AGENT);
      __threadfence();  // acquire: invalidate stale L2 lines
    }
    __syncthreads();

    const int t = layer ? (s - 1) : s;
    // ---- B sources ----
    const unsigned short* h0p_hi = wsu + O_H0_HI + ((unsigned)dir * 4 + ((s - 1) & 3)) * 32768u;
    const unsigned short* h0p_lo = wsu + O_H0_LO + ((unsigned)dir * 4 + ((s - 1) & 3)) * 32768u;

    float4v acc[2][4];
    #pragma unroll
    for (int mt = 0; mt < 2; ++mt)
      #pragma unroll
      for (int nt = 0; nt < 4; ++nt) acc[mt][nt] = (float4v)0.f;

    if (layer) {
      const int inp = (wid < 4);
      const unsigned short* bh_base;
      const unsigned short* bl_base;
      if (inp) { bh_base = h0p_hi; bl_base = h0p_lo; }
      else {
        bh_base = wsu + O_H1_HI + ((unsigned)dir * 2 + (s & 1)) * 32768u;
        bl_base = wsu + O_H1_LO + ((unsigned)dir * 2 + (s & 1)) * 32768u;
      }
      #pragma unroll
      for (int i = 0; i < 4; ++i) {
        const int kst_m = (wid * 4 + i) - (inp ? 0 : 16);
        const int ko = kst_m * 32 + lq * 8;
        #pragma unroll
        for (int nt = 0; nt < 4; ++nt) {
          const int b = nt * 16 + lr;
          short8v Bh = *(const short8v*)(bh_base + b * 512 + ko);
          short8v Bl = *(const short8v*)(bl_base + b * 512 + ko);
          #pragma unroll
          for (int mt = 0; mt < 2; ++mt) {
            acc[mt][nt] = MF(Ah[mt][i], Bh, acc[mt][nt]);
            acc[mt][nt] = MF(Al[mt][i], Bh, acc[mt][nt]);
            acc[mt][nt] = MF(Ah[mt][i], Bl, acc[mt][nt]);
          }
        }
      }
    } else {
      #pragma unroll
      for (int i = 0; i < 2; ++i) {
        const int ko = (wid * 2 + i) * 32 + lq * 8;
        #pragma unroll
        for (int nt = 0; nt < 4; ++nt) {
          const int b = nt * 16 + lr;
          short8v Bh = *(const short8v*)(h0p_hi + b * 512 + ko);
          short8v Bl = *(const short8v*)(h0p_lo + b * 512 + ko);
          #pragma unroll
          for (int mt = 0; mt < 2; ++mt) {
            acc[mt][nt] = MF(Ah[mt][i], Bh, acc[mt][nt]);
            acc[mt][nt] = MF(Al[mt][i], Bh, acc[mt][nt]);
            acc[mt][nt] = MF(Ah[mt][i], Bl, acc[mt][nt]);
          }
        }
      }
      if (wid < 4) {  // x contribution
        const int tx = dir ? (TT - 1 - t) : t;
        const int ko = wid * 32 + lq * 8;
        #pragma unroll
        for (int nt = 0; nt < 4; ++nt) {
          const int b = nt * 16 + lr;
          const float* xs = p.x + ((size_t)b * TT + tx) * DD + ko;
          short8v Bh, Bl;
          #pragma unroll
          for (int e = 0; e < 8; ++e) {
            const float xv = xs[e];
            const unsigned short hh = bf16_rne(xv);
            Bh[e] = (short)hh;
            Bl[e] = (short)bf16_rne(xv - bf16_f(hh));
          }
          #pragma unroll
          for (int mt = 0; mt < 2; ++mt) {
            acc[mt][nt] = MF(Ah[mt][2], Bh, acc[mt][nt]);
            acc[mt][nt] = MF(Al[mt][2], Bh, acc[mt][nt]);
            acc[mt][nt] = MF(Ah[mt][2], Bl, acc[mt][nt]);
          }
        }
      }
    }

    // ---- write partials to LDS ----
    #pragma unroll
    for (int mt = 0; mt < 2; ++mt)
      #pragma unroll
      for (int nt = 0; nt < 4; ++nt)
        #pragma unroll
        for (int q = 0; q < 4; ++q)
          red[(wid * 32 + mt * 16 + lq * 4 + q) * 66 + nt * 16 + lr] = acc[mt][nt][q];
    __syncthreads();

    // ---- reduce + gates + store h (thread: j=jth, b=bth) ----
    {
      float Sr = 0.f, Sz = 0.f, Sni = 0.f, Snh = 0.f;
      #pragma unroll
      for (int w = 0; w < 8; ++w) {
        Sr  += red[(w * 32 + jth) * 66 + bth];
        Sz  += red[(w * 32 + 8 + jth) * 66 + bth];
        Sni += red[(w * 32 + 16 + jth) * 66 + bth];
        Snh += red[(w * 32 + 24 + jth) * 66 + bth];
      }
      const float r = 1.f / (1.f + __expf(-(Sr + br)));
      const float z = 1.f / (1.f + __expf(-(Sz + bz)));
      const float n = tanhf(Sni + bnih + r * (Snh + bnhh));
      const unsigned idx = (unsigned)bth * 512u + (unsigned)(j0 + jth);
      unsigned short *hw_hi, *hw_lo; const unsigned short *hp_hi, *hp_lo;
      if (layer) {
        hp_hi = wsu + O_H1_HI + ((unsigned)dir * 2 + (s & 1)) * 32768u;
        hp_lo = wsu + O_H1_LO + ((unsigned)dir * 2 + (s & 1)) * 32768u;
        hw_hi = wsu + O_H1_HI + ((unsigned)dir * 2 + ((s - 1) & 1)) * 32768u;
        hw_lo = wsu + O_H1_LO + ((unsigned)dir * 2 + ((s - 1) & 1)) * 32768u;
      } else {
        hp_hi = wsu + O_H0_HI + ((unsigned)dir * 4 + ((s - 1) & 3)) * 32768u;
        hp_lo = wsu + O_H0_LO + ((unsigned)dir * 4 + ((s - 1) & 3)) * 32768u;
        hw_hi = wsu + O_H0_HI + ((unsigned)dir * 4 + (s & 3)) * 32768u;
        hw_lo = wsu + O_H0_LO + ((unsigned)dir * 4 + (s & 3)) * 32768u;
      }
      const float hp = bf16_f(hp_hi[idx]) + bf16_f(hp_lo[idx]);
      const float h = (1.f - z) * n + z * hp;
      const unsigned short hh = bf16_rne(h);
      hw_hi[idx] = hh;
      hw_lo[idx] = bf16_rne(h - bf16_f(hh));
    }
    __threadfence();   // release: write back dirty L2
    __syncthreads();
    if (tid == 0)
      __hip_atomic_store(own + jt, s, __ATOMIC_RELEASE, __HIP_MEMORY_SCOPE_AGENT);
  }
}

// ---- prep: fp32 -> bf16 hi/lo split ----
__global__ void cvt_k(const float* __restrict__ src, unsigned short* __restrict__ hi,
                      unsigned short* __restrict__ lo, int n) {
  for (int i = blockIdx.x * blockDim.x + threadIdx.x; i < n; i += gridDim.x * blockDim.x) {
    const float w = src[i];
    const unsigned short h = bf16_rne(w);
    hi[i] = h;
    lo[i] = bf16_rne(w - bf16_f(h));
  }
}

__global__ void init_k(unsigned short* wsu, int* flags) {
  for (unsigned i = blockIdx.x * blockDim.x + threadIdx.x; i < H_ZERO_N; i += gridDim.x * blockDim.x)
    wsu[O_H0_HI + i] = 0;
  const unsigned g = blockIdx.x * blockDim.x + threadIdx.x;
  if (g < 256) flags[g] = ((g >> 6) & 1) ? 0 : -1;  // L1 units start at 0, L0 at -1
}

// hidden = [h0_f | h1_f | h0_b | h1_b]; h0 final slot 3, h1 final slot 1
__global__ void gather_k(const unsigned short* __restrict__ wsu, float* __restrict__ fc_in) {
  const int idx = blockIdx.x * blockDim.x + threadIdx.x;  // 64*2048
  const int b = idx >> 11, c = idx & 2047;
  const int seg = c >> 9, cc = c & 511;
  unsigned base_hi, base_lo;
  if (seg == 0)      { base_hi = O_H0_HI + 3u * 32768u;              base_lo = O_H0_LO + 3u * 32768u; }
  else if (seg == 1) { base_hi = O_H1_HI + 1u * 32768u;              base_lo = O_H1_LO + 1u * 32768u; }
  else if (seg == 2) { base_hi = O_H0_HI + (4u + 3u) * 32768u;       base_lo = O_H0_LO + (4u + 3u) * 32768u; }
  else               { base_hi = O_H1_HI + (2u + 1u) * 32768u;       base_lo = O_H1_LO + (2u + 1u) * 32768u; }
  const unsigned o = (unsigned)b * 512u + (unsigned)cc;
  fc_in[idx] = bf16_f(wsu[base_hi + o]) + bf16_f(wsu[base_lo + o]);
}

__global__ void fc_k(const float* __restrict__ in, const float* __restrict__ W,
                     const float* __restrict__ bias, float* __restrict__ out,
                     int K, int N, int leaky) {
  const int idx = blockIdx.x * blockDim.x + threadIdx.x;
  const int b = idx / N;
  const int n = idx - b * N;
  if (b >= BB) return;
  const float* ir = in + (size_t)b * K;
  const float* wr = W + (size_t)n * K;
  float acc = 0.f;
  for (int k = 0; k < K; k += 4) {
    const float4 a = *(const float4*)(ir + k);
    const float4 w = *(const float4*)(wr + k);
    acc += a.x * w.x + a.y * w.y + a.z * w.z + a.w * w.w;
  }
  acc += bias[n];
  if (leaky) acc = acc > 0.f ? acc : 0.01f * acc;
  out[idx] = acc;
}

extern "C" void kernel_launch(void* const* d_in, const int* in_sizes, int n_in,
                              void* d_out, int out_size, void* d_ws, size_t ws_size,
                              hipStream_t stream) {
  (void)in_sizes; (void)n_in; (void)out_size; (void)ws_size;

  PP P;
  P.x = (const float*)d_in[0];
  const float* Wih[4]; const float* Whh[4];
  for (int dir = 0; dir < 2; ++dir)
    for (int l = 0; l < 2; ++l) {
      const int base = 1 + (dir * 2 + l) * 4;
      const int u = dir * 2 + l;
      Wih[u] = (const float*)d_in[base + 0];
      Whh[u] = (const float*)d_in[base + 1];
      P.bih[u] = (const float*)d_in[base + 2];
      P.bhh[u] = (const float*)d_in[base + 3];
    }
  const float* Wfc0 = (const float*)d_in[17];
  const float* bfc0 = (const float*)d_in[18];
  const float* Wfc1 = (const float*)d_in[19];
  const float* bfc1 = (const float*)d_in[20];
  const float* Wfc2 = (const float*)d_in[21];
  const float* bfc2 = (const float*)d_in[22];

  unsigned short* wsu = (unsigned short*)d_ws;
  float* wsf = (float*)d_ws;
  int* flags = (int*)(wsf + OI_FLAGS);
  float* fc_in = wsf + OF_FCIN;
  float* fc1o  = wsf + OF_FC1O;
  float* fc2o  = wsf + OF_FC2O;
  P.wsu = wsu; P.flags = flags;

  hipFuncSetAttribute((const void*)gru_mfma,
                      hipFuncAttributeMaxDynamicSharedMemorySize, DYN_LDS);

  // ---- prep: weight split + h/flag init ----
  for (int u = 0; u < 4; ++u)
    hipLaunchKernelGGL(cvt_k, dim3(512), dim3(256), 0, stream,
                       Whh[u], wsu + O_WHH_HI + u * 786432u, wsu + O_WHH_LO + u * 786432u, 786432);
  for (int dir = 0; dir < 2; ++dir) {
    hipLaunchKernelGGL(cvt_k, dim3(512), dim3(256), 0, stream,
                       Wih[dir * 2 + 1], wsu + O_WIH1_HI + dir * 786432u, wsu + O_WIH1_LO + dir * 786432u, 786432);
    hipLaunchKernelGGL(cvt_k, dim3(256), dim3(256), 0, stream,
                       Wih[dir * 2 + 0], wsu + O_WIH0_HI + dir * 196608u, wsu + O_WIH0_LO + dir * 196608u, 196608);
  }
  hipLaunchKernelGGL(init_k, dim3(512), dim3(256), 0, stream, wsu, flags);

  // ---- persistent recurrence ----
  hipLaunchKernelGGL(gru_mfma, dim3(256), dim3(512), DYN_LDS, stream, P);

  // ---- FC head ----
  hipLaunchKernelGGL(gather_k, dim3(512), dim3(256), 0, stream, wsu, fc_in);
  hipLaunchKernelGGL(fc_k, dim3(256), dim3(256), 0, stream, fc_in, Wfc0, bfc0, fc1o, 2048, 1024, 1);
  hipLaunchKernelGGL(fc_k, dim3(128), dim3(256), 0, stream, fc1o, Wfc1, bfc1, fc2o, 1024, 512, 1);
  hipLaunchKernelGGL(fc_k, dim3(1), dim3(256), 0, stream, fc2o, Wfc2, bfc2, (float*)d_out, 512, 1, 0);
}

// Round 4
// 39395.117 us; speedup vs baseline: 2.4292x; 2.4292x over previous
//
#include <hip/hip_runtime.h>
#include <math.h>

typedef __attribute__((ext_vector_type(8))) short short8v;
typedef __attribute__((ext_vector_type(4))) float float4v;

#define BB 64
#define TT 1024
#define DD 128
#define HH 512

// ---- ws layout: ushort (bf16) region, element offsets ----
#define O_WHH_HI  0u         // [4 units][1536][512]
#define O_WHH_LO  3145728u
#define O_WIH1_HI 6291456u   // [2 dir][1536][512]
#define O_WIH1_LO 7864320u
#define O_WIH0_HI 9437184u   // [2 dir][1536][128]
#define O_WIH0_LO 9830400u
#define O_H0_HI   10223616u  // [2 dir][4 slot][64 b][512 j]
#define O_H0_LO   10485760u
#define O_H1_HI   10747904u  // [2 dir][2 slot][64 b][512 j]
#define O_H1_LO   10878976u
#define H_ZERO_N  786432u    // ushorts to zero from O_H0_HI
// ---- float region (ws as float*) ----
#define OF_FCIN   5505024u   // 131072 f
#define OF_FC1O   5636096u   //  65536 f
#define OF_FC2O   5701632u   //  32768 f
#define OI_FLAGS  5734400u   // 256 ints

#define DYN_LDS   67584      // [8][32][66] f32 reduction buffer

struct PP {
  const float* x;
  const float* bih[4];
  const float* bhh[4];
  unsigned short* wsu;
  int* flags;
};

__device__ __forceinline__ unsigned short bf16_rne(float f) {
  unsigned u = __builtin_bit_cast(unsigned, f);
  u += 0x7FFFu + ((u >> 16) & 1u);
  return (unsigned short)(u >> 16);
}
__device__ __forceinline__ float bf16_f(unsigned short h) {
  unsigned u = ((unsigned)h) << 16;
  return __builtin_bit_cast(float, u);
}
__device__ __forceinline__ float4v MF(short8v a, short8v b, float4v c) {
  return __builtin_amdgcn_mfma_f32_16x16x32_bf16(a, b, c, 0, 0, 0);
}

// ---- agent-scope (sc1, L2-bypassing, fence-free) shared-state access ----
__device__ __forceinline__ unsigned ald_u32(const unsigned short* p) {
  return __hip_atomic_load((const unsigned*)p, __ATOMIC_RELAXED, __HIP_MEMORY_SCOPE_AGENT);
}
// load 8 consecutive bf16 (16B) from a plane as one MFMA fragment
__device__ __forceinline__ short8v ald8(const unsigned short* p) {
  union { unsigned u[4]; short8v v; } r;
  r.u[0] = ald_u32(p);
  r.u[1] = ald_u32(p + 2);
  r.u[2] = ald_u32(p + 4);
  r.u[3] = ald_u32(p + 6);
  return r.v;
}
__device__ __forceinline__ unsigned short ald_u16(const unsigned short* p) {
  return __hip_atomic_load(p, __ATOMIC_RELAXED, __HIP_MEMORY_SCOPE_AGENT);
}
__device__ __forceinline__ void ast_u16(unsigned short* p, unsigned short v) {
  __hip_atomic_store(p, v, __ATOMIC_RELAXED, __HIP_MEMORY_SCOPE_AGENT);
}

// row within stacked-[3*512] W for local row rl (0..31); -1 => zero frag
__device__ __forceinline__ int rowmap(int rl, int inp, int j0) {
  if (rl < 8)  return j0 + rl;
  if (rl < 16) return 512 + j0 + (rl - 8);
  if (rl < 24) return inp ? (1024 + j0 + rl - 16) : -1;
  return inp ? -1 : (1024 + j0 + rl - 24);
}
__device__ __forceinline__ short8v ldA(const unsigned short* W, int K, int row, int kofs) {
  return *(const short8v*)(W + (size_t)row * K + kofs);
}

// 256 blocks x 512 thr. u=bid>>6 (dir*2+layer), jt=bid&63 -> 8 j's.
// 8 waves split K; MFMA C[32 rows x 64 b]; rows: 0-7 r, 8-15 z, 16-23 n_ih, 24-31 n_hh.
__global__ __launch_bounds__(512) void gru_mfma(PP p) {
  extern __shared__ float red[];  // [8][32][66]
  const int bid = blockIdx.x;
  const int u = bid >> 6, dir = u >> 1, layer = u & 1;
  const int jt = bid & 63, j0 = jt * 8;
  const int tid = threadIdx.x, wid = tid >> 6, lane = tid & 63;
  const int lr = lane & 15, lq = lane >> 4;
  unsigned short* wsu = p.wsu;

  // ---- preload A fragments (weights) into VGPRs (normal cached loads) ----
  short8v Ah[2][4], Al[2][4];
  #pragma unroll
  for (int mt = 0; mt < 2; ++mt)
    #pragma unroll
    for (int i = 0; i < 4; ++i) { Ah[mt][i] = (short8v)0; Al[mt][i] = (short8v)0; }

  if (layer) {
    const int inp = (wid < 4);  // waves 0-3: input part (Wih_l1), 4-7: hidden (Whh)
    const unsigned short* Whi = inp ? (wsu + O_WIH1_HI + dir * 786432u)
                                    : (wsu + O_WHH_HI + (unsigned)u * 786432u);
    const unsigned short* Wlo = inp ? (wsu + O_WIH1_LO + dir * 786432u)
                                    : (wsu + O_WHH_LO + (unsigned)u * 786432u);
    #pragma unroll
    for (int i = 0; i < 4; ++i) {
      const int kst_m = (wid * 4 + i) - (inp ? 0 : 16);
      const int kofs = kst_m * 32 + lq * 8;
      #pragma unroll
      for (int mt = 0; mt < 2; ++mt) {
        const int row = rowmap(mt * 16 + lr, inp, j0);
        if (row >= 0) { Ah[mt][i] = ldA(Whi, 512, row, kofs); Al[mt][i] = ldA(Wlo, 512, row, kofs); }
      }
    }
  } else {
    const unsigned short* Whi = wsu + O_WHH_HI + (unsigned)u * 786432u;
    const unsigned short* Wlo = wsu + O_WHH_LO + (unsigned)u * 786432u;
    #pragma unroll
    for (int i = 0; i < 2; ++i) {
      const int kofs = (wid * 2 + i) * 32 + lq * 8;
      #pragma unroll
      for (int mt = 0; mt < 2; ++mt) {
        const int row = rowmap(mt * 16 + lr, 0, j0);
        if (row >= 0) { Ah[mt][i] = ldA(Whi, 512, row, kofs); Al[mt][i] = ldA(Wlo, 512, row, kofs); }
      }
    }
    if (wid < 4) {  // x part: K=128, wave wid owns kst wid
      const unsigned short* Xhi = wsu + O_WIH0_HI + dir * 196608u;
      const unsigned short* Xlo = wsu + O_WIH0_LO + dir * 196608u;
      const int kofs = wid * 32 + lq * 8;
      #pragma unroll
      for (int mt = 0; mt < 2; ++mt) {
        const int row = rowmap(mt * 16 + lr, 1, j0);
        if (row >= 0) { Ah[mt][2] = ldA(Xhi, 128, row, kofs); Al[mt][2] = ldA(Xlo, 128, row, kofs); }
      }
    }
  }

  // ---- biases (per gate-thread j) ----
  const int jth = tid >> 6, bth = tid & 63;  // gate stage: 8 j x 64 b
  const float br   = p.bih[u][j0 + jth] + p.bhh[u][j0 + jth];
  const float bz   = p.bih[u][512 + j0 + jth] + p.bhh[u][512 + j0 + jth];
  const float bnih = p.bih[u][1024 + j0 + jth];
  const float bnhh = p.bhh[u][1024 + j0 + jth];

  int* own = p.flags + u * 64;
  int* sib = p.flags + (layer ? (u - 1) : (u + 1)) * 64;
  const int sBeg = layer ? 1 : 0;
  const int sEnd = layer ? TT : (TT - 1);

  for (int s = sBeg; s <= sEnd; ++s) {
    // ---- wait for dependencies (wave 0 polls; relaxed sc1 loads, NO fences) ----
    if (wid == 0) {
      const int T1 = s - 1;
      const int T2 = layer ? (s - 1) : (s - 3);
      int iter = 0;
      while (true) {
        int f1 = __hip_atomic_load(own + lane, __ATOMIC_RELAXED, __HIP_MEMORY_SCOPE_AGENT);
        int f2 = __hip_atomic_load(sib + lane, __ATOMIC_RELAXED, __HIP_MEMORY_SCOPE_AGENT);
        if (__all(f1 >= T1 && f2 >= T2)) break;
        if (++iter > 1000000) {  // failsafe: terminate (results wrong but no hang)
          if (lane == 0)
            __hip_atomic_store(own + jt, 1 << 29, __ATOMIC_RELAXED, __HIP_MEMORY_SCOPE_AGENT);
          break;
        }
        __builtin_amdgcn_s_sleep(2);
      }
    }
    __syncthreads();

    const int t = layer ? (s - 1) : s;
    const unsigned short* h0p_hi = wsu + O_H0_HI + ((unsigned)dir * 4 + ((s - 1) & 3)) * 32768u;
    const unsigned short* h0p_lo = wsu + O_H0_LO + ((unsigned)dir * 4 + ((s - 1) & 3)) * 32768u;

    float4v acc[2][4];
    #pragma unroll
    for (int mt = 0; mt < 2; ++mt)
      #pragma unroll
      for (int nt = 0; nt < 4; ++nt) acc[mt][nt] = (float4v)0.f;

    if (layer) {
      const int inp = (wid < 4);
      const unsigned short* bh_base;
      const unsigned short* bl_base;
      if (inp) { bh_base = h0p_hi; bl_base = h0p_lo; }
      else {
        bh_base = wsu + O_H1_HI + ((unsigned)dir * 2 + (s & 1)) * 32768u;
        bl_base = wsu + O_H1_LO + ((unsigned)dir * 2 + (s & 1)) * 32768u;
      }
      #pragma unroll
      for (int i = 0; i < 4; ++i) {
        const int kst_m = (wid * 4 + i) - (inp ? 0 : 16);
        const int ko = kst_m * 32 + lq * 8;
        #pragma unroll
        for (int nt = 0; nt < 4; ++nt) {
          const int b = nt * 16 + lr;
          short8v Bh = ald8(bh_base + b * 512 + ko);
          short8v Bl = ald8(bl_base + b * 512 + ko);
          #pragma unroll
          for (int mt = 0; mt < 2; ++mt) {
            acc[mt][nt] = MF(Ah[mt][i], Bh, acc[mt][nt]);
            acc[mt][nt] = MF(Al[mt][i], Bh, acc[mt][nt]);
            acc[mt][nt] = MF(Ah[mt][i], Bl, acc[mt][nt]);
          }
        }
      }
    } else {
      #pragma unroll
      for (int i = 0; i < 2; ++i) {
        const int ko = (wid * 2 + i) * 32 + lq * 8;
        #pragma unroll
        for (int nt = 0; nt < 4; ++nt) {
          const int b = nt * 16 + lr;
          short8v Bh = ald8(h0p_hi + b * 512 + ko);
          short8v Bl = ald8(h0p_lo + b * 512 + ko);
          #pragma unroll
          for (int mt = 0; mt < 2; ++mt) {
            acc[mt][nt] = MF(Ah[mt][i], Bh, acc[mt][nt]);
            acc[mt][nt] = MF(Al[mt][i], Bh, acc[mt][nt]);
            acc[mt][nt] = MF(Ah[mt][i], Bl, acc[mt][nt]);
          }
        }
      }
      if (wid < 4) {  // x contribution (normal cached loads; x is read-only input)
        const int tx = dir ? (TT - 1 - t) : t;
        const int ko = wid * 32 + lq * 8;
        #pragma unroll
        for (int nt = 0; nt < 4; ++nt) {
          const int b = nt * 16 + lr;
          const float* xs = p.x + ((size_t)b * TT + tx) * DD + ko;
          short8v Bh, Bl;
          #pragma unroll
          for (int e = 0; e < 8; ++e) {
            const float xv = xs[e];
            const unsigned short hh = bf16_rne(xv);
            Bh[e] = (short)hh;
            Bl[e] = (short)bf16_rne(xv - bf16_f(hh));
          }
          #pragma unroll
          for (int mt = 0; mt < 2; ++mt) {
            acc[mt][nt] = MF(Ah[mt][2], Bh, acc[mt][nt]);
            acc[mt][nt] = MF(Al[mt][2], Bh, acc[mt][nt]);
            acc[mt][nt] = MF(Ah[mt][2], Bl, acc[mt][nt]);
          }
        }
      }
    }

    // ---- write partials to LDS ----
    #pragma unroll
    for (int mt = 0; mt < 2; ++mt)
      #pragma unroll
      for (int nt = 0; nt < 4; ++nt)
        #pragma unroll
        for (int q = 0; q < 4; ++q)
          red[(wid * 32 + mt * 16 + lq * 4 + q) * 66 + nt * 16 + lr] = acc[mt][nt][q];
    __syncthreads();

    // ---- reduce + gates + store h (thread: j=jth, b=bth) ----
    {
      float Sr = 0.f, Sz = 0.f, Sni = 0.f, Snh = 0.f;
      #pragma unroll
      for (int w = 0; w < 8; ++w) {
        Sr  += red[(w * 32 + jth) * 66 + bth];
        Sz  += red[(w * 32 + 8 + jth) * 66 + bth];
        Sni += red[(w * 32 + 16 + jth) * 66 + bth];
        Snh += red[(w * 32 + 24 + jth) * 66 + bth];
      }
      const float r = 1.f / (1.f + __expf(-(Sr + br)));
      const float z = 1.f / (1.f + __expf(-(Sz + bz)));
      const float n = tanhf(Sni + bnih + r * (Snh + bnhh));
      const unsigned idx = (unsigned)bth * 512u + (unsigned)(j0 + jth);
      unsigned short *hw_hi, *hw_lo; const unsigned short *hp_hi, *hp_lo;
      if (layer) {
        hp_hi = wsu + O_H1_HI + ((unsigned)dir * 2 + (s & 1)) * 32768u;
        hp_lo = wsu + O_H1_LO + ((unsigned)dir * 2 + (s & 1)) * 32768u;
        hw_hi = wsu + O_H1_HI + ((unsigned)dir * 2 + ((s - 1) & 1)) * 32768u;
        hw_lo = wsu + O_H1_LO + ((unsigned)dir * 2 + ((s - 1) & 1)) * 32768u;
      } else {
        hp_hi = wsu + O_H0_HI + ((unsigned)dir * 4 + ((s - 1) & 3)) * 32768u;
        hp_lo = wsu + O_H0_LO + ((unsigned)dir * 4 + ((s - 1) & 3)) * 32768u;
        hw_hi = wsu + O_H0_HI + ((unsigned)dir * 4 + (s & 3)) * 32768u;
        hw_lo = wsu + O_H0_LO + ((unsigned)dir * 4 + (s & 3)) * 32768u;
      }
      const float hp = bf16_f(ald_u16(hp_hi + idx)) + bf16_f(ald_u16(hp_lo + idx));
      const float h = (1.f - z) * n + z * hp;
      const unsigned short hh = bf16_rne(h);
      ast_u16(hw_hi + idx, hh);
      ast_u16(hw_lo + idx, bf16_rne(h - bf16_f(hh)));
    }
    // __syncthreads drains every wave's vmcnt(0) (compiler-enforced) =>
    // all sc1 h-stores are at the coherence point before the flag store.
    __syncthreads();
    if (tid == 0)
      __hip_atomic_store(own + jt, s, __ATOMIC_RELAXED, __HIP_MEMORY_SCOPE_AGENT);
  }
}

// ---- prep: fp32 -> bf16 hi/lo split ----
__global__ void cvt_k(const float* __restrict__ src, unsigned short* __restrict__ hi,
                      unsigned short* __restrict__ lo, int n) {
  for (int i = blockIdx.x * blockDim.x + threadIdx.x; i < n; i += gridDim.x * blockDim.x) {
    const float w = src[i];
    const unsigned short h = bf16_rne(w);
    hi[i] = h;
    lo[i] = bf16_rne(w - bf16_f(h));
  }
}

__global__ void init_k(unsigned short* wsu, int* flags) {
  for (unsigned i = blockIdx.x * blockDim.x + threadIdx.x; i < H_ZERO_N; i += gridDim.x * blockDim.x)
    wsu[O_H0_HI + i] = 0;
  const unsigned g = blockIdx.x * blockDim.x + threadIdx.x;
  if (g < 256) flags[g] = ((g >> 6) & 1) ? 0 : -1;  // L1 units start at 0, L0 at -1
}

// hidden = [h0_f | h1_f | h0_b | h1_b]; h0 final slot 3, h1 final slot 1
__global__ void gather_k(const unsigned short* __restrict__ wsu, float* __restrict__ fc_in) {
  const int idx = blockIdx.x * blockDim.x + threadIdx.x;  // 64*2048
  const int b = idx >> 11, c = idx & 2047;
  const int seg = c >> 9, cc = c & 511;
  unsigned base_hi, base_lo;
  if (seg == 0)      { base_hi = O_H0_HI + 3u * 32768u;              base_lo = O_H0_LO + 3u * 32768u; }
  else if (seg == 1) { base_hi = O_H1_HI + 1u * 32768u;              base_lo = O_H1_LO + 1u * 32768u; }
  else if (seg == 2) { base_hi = O_H0_HI + (4u + 3u) * 32768u;       base_lo = O_H0_LO + (4u + 3u) * 32768u; }
  else               { base_hi = O_H1_HI + (2u + 1u) * 32768u;       base_lo = O_H1_LO + (2u + 1u) * 32768u; }
  const unsigned o = (unsigned)b * 512u + (unsigned)cc;
  fc_in[idx] = bf16_f(wsu[base_hi + o]) + bf16_f(wsu[base_lo + o]);
}

__global__ void fc_k(const float* __restrict__ in, const float* __restrict__ W,
                     const float* __restrict__ bias, float* __restrict__ out,
                     int K, int N, int leaky) {
  const int idx = blockIdx.x * blockDim.x + threadIdx.x;
  const int b = idx / N;
  const int n = idx - b * N;
  if (b >= BB) return;
  const float* ir = in + (size_t)b * K;
  const float* wr = W + (size_t)n * K;
  float acc = 0.f;
  for (int k = 0; k < K; k += 4) {
    const float4 a = *(const float4*)(ir + k);
    const float4 w = *(const float4*)(wr + k);
    acc += a.x * w.x + a.y * w.y + a.z * w.z + a.w * w.w;
  }
  acc += bias[n];
  if (leaky) acc = acc > 0.f ? acc : 0.01f * acc;
  out[idx] = acc;
}

extern "C" void kernel_launch(void* const* d_in, const int* in_sizes, int n_in,
                              void* d_out, int out_size, void* d_ws, size_t ws_size,
                              hipStream_t stream) {
  (void)in_sizes; (void)n_in; (void)out_size; (void)ws_size;

  PP P;
  P.x = (const float*)d_in[0];
  const float* Wih[4]; const float* Whh[4];
  for (int dir = 0; dir < 2; ++dir)
    for (int l = 0; l < 2; ++l) {
      const int base = 1 + (dir * 2 + l) * 4;
      const int u = dir * 2 + l;
      Wih[u] = (const float*)d_in[base + 0];
      Whh[u] = (const float*)d_in[base + 1];
      P.bih[u] = (const float*)d_in[base + 2];
      P.bhh[u] = (const float*)d_in[base + 3];
    }
  const float* Wfc0 = (const float*)d_in[17];
  const float* bfc0 = (const float*)d_in[18];
  const float* Wfc1 = (const float*)d_in[19];
  const float* bfc1 = (const float*)d_in[20];
  const float* Wfc2 = (const float*)d_in[21];
  const float* bfc2 = (const float*)d_in[22];

  unsigned short* wsu = (unsigned short*)d_ws;
  float* wsf = (float*)d_ws;
  int* flags = (int*)(wsf + OI_FLAGS);
  float* fc_in = wsf + OF_FCIN;
  float* fc1o  = wsf + OF_FC1O;
  float* fc2o  = wsf + OF_FC2O;
  P.wsu = wsu; P.flags = flags;

  hipFuncSetAttribute((const void*)gru_mfma,
                      hipFuncAttributeMaxDynamicSharedMemorySize, DYN_LDS);

  // ---- prep: weight split + h/flag init ----
  for (int u = 0; u < 4; ++u)
    hipLaunchKernelGGL(cvt_k, dim3(512), dim3(256), 0, stream,
                       Whh[u], wsu + O_WHH_HI + u * 786432u, wsu + O_WHH_LO + u * 786432u, 786432);
  for (int dir = 0; dir < 2; ++dir) {
    hipLaunchKernelGGL(cvt_k, dim3(512), dim3(256), 0, stream,
                       Wih[dir * 2 + 1], wsu + O_WIH1_HI + dir * 786432u, wsu + O_WIH1_LO + dir * 786432u, 786432);
    hipLaunchKernelGGL(cvt_k, dim3(256), dim3(256), 0, stream,
                       Wih[dir * 2 + 0], wsu + O_WIH0_HI + dir * 196608u, wsu + O_WIH0_LO + dir * 196608u, 196608);
  }
  hipLaunchKernelGGL(init_k, dim3(512), dim3(256), 0, stream, wsu, flags);

  // ---- persistent recurrence ----
  hipLaunchKernelGGL(gru_mfma, dim3(256), dim3(512), DYN_LDS, stream, P);

  // ---- FC head ----
  hipLaunchKernelGGL(gather_k, dim3(512), dim3(256), 0, stream, wsu, fc_in);
  hipLaunchKernelGGL(fc_k, dim3(256), dim3(256), 0, stream, fc_in, Wfc0, bfc0, fc1o, 2048, 1024, 1);
  hipLaunchKernelGGL(fc_k, dim3(128), dim3(256), 0, stream, fc1o, Wfc1, bfc1, fc2o, 1024, 512, 1);
  hipLaunchKernelGGL(fc_k, dim3(1), dim3(256), 0, stream, fc2o, Wfc2, bfc2, (float*)d_out, 512, 1, 0);
}

// Round 5
// 11760.651 us; speedup vs baseline: 8.1371x; 3.3497x over previous
//
#include <hip/hip_runtime.h>
#include <math.h>

typedef __attribute__((ext_vector_type(8))) short short8v;
typedef __attribute__((ext_vector_type(4))) float float4v;

#define BB 64
#define TT 1024
#define DD 128
#define HH 512

// ---- ushort (bf16) region: weights (element offsets) ----
#define O_WHH_HI  0u         // [4 units][1536][512]
#define O_WHH_LO  3145728u
#define O_WIH1_HI 6291456u   // [2 dir][1536][512]
#define O_WIH1_LO 7864320u
#define O_WIH0_HI 9437184u   // [2 dir][1536][128]
#define O_WIH0_LO 9830400u   // ends at 10223616 ushorts
// ---- 4-byte-word region (ws as unsigned*/float*), word offsets ----
#define O_H0_W    5111808u   // [2 dir][4 slot][512 k][64 b] packed hi|lo u32
#define O_H1_W    5373952u   // [2 dir][2 slot][512 k][64 b]
#define O_FLAGS_W 5505024u   // 256 ints
#define O_FCIN_W  5505280u   // 131072 f
#define O_FC1O_W  5636352u   //  65536 f
#define O_FC2O_W  5701888u   //  32768 f
#define H_ZERO_W  393216u    // words to zero from O_H0_W

#define DYN_LDS   69632      // [8][32] x stride-68 f32 reduction buffer

struct PP {
  const float* x;
  const float* bih[4];
  const float* bhh[4];
  unsigned short* wsu;   // weight planes
  unsigned* ws32;        // packed h region
  int* flags;
};

__device__ __forceinline__ unsigned short bf16_rne(float f) {
  unsigned u = __builtin_bit_cast(unsigned, f);
  u += 0x7FFFu + ((u >> 16) & 1u);
  return (unsigned short)(u >> 16);
}
__device__ __forceinline__ float bf16_f(unsigned short h) {
  unsigned u = ((unsigned)h) << 16;
  return __builtin_bit_cast(float, u);
}
__device__ __forceinline__ float4v MF(short8v a, short8v b, float4v c) {
  return __builtin_amdgcn_mfma_f32_16x16x32_bf16(a, b, c, 0, 0, 0);
}
// agent-scope relaxed (coherence point, no fences)
__device__ __forceinline__ unsigned ald_w(const unsigned* p) {
  return __hip_atomic_load(p, __ATOMIC_RELAXED, __HIP_MEMORY_SCOPE_AGENT);
}
__device__ __forceinline__ void ast_w(unsigned* p, unsigned v) {
  __hip_atomic_store(p, v, __ATOMIC_RELAXED, __HIP_MEMORY_SCOPE_AGENT);
}
// load B fragment (8 k-elems for lane's batch col b) from packed [k][64] plane
__device__ __forceinline__ void ldB(const unsigned* base, int ko, int b,
                                    short8v& Bh, short8v& Bl) {
  #pragma unroll
  for (int e = 0; e < 8; ++e) {
    const unsigned w = ald_w(base + (unsigned)(ko + e) * 64u + (unsigned)b);
    Bh[e] = (short)(w >> 16);
    Bl[e] = (short)(w & 0xFFFFu);
  }
}

// row within stacked-[3*512] W for local row rl (0..31); -1 => zero frag
__device__ __forceinline__ int rowmap(int rl, int inp, int j0) {
  if (rl < 8)  return j0 + rl;
  if (rl < 16) return 512 + j0 + (rl - 8);
  if (rl < 24) return inp ? (1024 + j0 + rl - 16) : -1;
  return inp ? -1 : (1024 + j0 + rl - 24);
}
__device__ __forceinline__ short8v ldA(const unsigned short* W, int K, int row, int kofs) {
  return *(const short8v*)(W + (size_t)row * K + kofs);
}

// 256 blocks x 512 thr. u=bid>>6 (dir*2+layer), jt=bid&63 -> 8 j's.
// 8 waves split K; MFMA C[32 rows x 64 b]; rows: 0-7 r, 8-15 z, 16-23 n_ih, 24-31 n_hh.
__global__ __launch_bounds__(512) void gru_mfma(PP p) {
  extern __shared__ float red[];  // [8][32] stride 68
  const int bid = blockIdx.x;
  const int u = bid >> 6, dir = u >> 1, layer = u & 1;
  const int jt = bid & 63, j0 = jt * 8;
  const int tid = threadIdx.x, wid = tid >> 6, lane = tid & 63;
  const int lr = lane & 15, lq = lane >> 4;
  unsigned short* wsu = p.wsu;
  unsigned* ws32 = p.ws32;

  // ---- preload A fragments (weights) into VGPRs (normal cached loads) ----
  short8v Ah[2][4], Al[2][4];
  #pragma unroll
  for (int mt = 0; mt < 2; ++mt)
    #pragma unroll
    for (int i = 0; i < 4; ++i) { Ah[mt][i] = (short8v)0; Al[mt][i] = (short8v)0; }

  if (layer) {
    const int inp = (wid < 4);  // waves 0-3: input part (Wih_l1), 4-7: hidden (Whh)
    const unsigned short* Whi = inp ? (wsu + O_WIH1_HI + dir * 786432u)
                                    : (wsu + O_WHH_HI + (unsigned)u * 786432u);
    const unsigned short* Wlo = inp ? (wsu + O_WIH1_LO + dir * 786432u)
                                    : (wsu + O_WHH_LO + (unsigned)u * 786432u);
    #pragma unroll
    for (int i = 0; i < 4; ++i) {
      const int kst_m = (wid * 4 + i) - (inp ? 0 : 16);
      const int kofs = kst_m * 32 + lq * 8;
      #pragma unroll
      for (int mt = 0; mt < 2; ++mt) {
        const int row = rowmap(mt * 16 + lr, inp, j0);
        if (row >= 0) { Ah[mt][i] = ldA(Whi, 512, row, kofs); Al[mt][i] = ldA(Wlo, 512, row, kofs); }
      }
    }
  } else {
    const unsigned short* Whi = wsu + O_WHH_HI + (unsigned)u * 786432u;
    const unsigned short* Wlo = wsu + O_WHH_LO + (unsigned)u * 786432u;
    #pragma unroll
    for (int i = 0; i < 2; ++i) {
      const int kofs = (wid * 2 + i) * 32 + lq * 8;
      #pragma unroll
      for (int mt = 0; mt < 2; ++mt) {
        const int row = rowmap(mt * 16 + lr, 0, j0);
        if (row >= 0) { Ah[mt][i] = ldA(Whi, 512, row, kofs); Al[mt][i] = ldA(Wlo, 512, row, kofs); }
      }
    }
    if (wid < 4) {  // x part: K=128, wave wid owns kst wid
      const unsigned short* Xhi = wsu + O_WIH0_HI + dir * 196608u;
      const unsigned short* Xlo = wsu + O_WIH0_LO + dir * 196608u;
      const int kofs = wid * 32 + lq * 8;
      #pragma unroll
      for (int mt = 0; mt < 2; ++mt) {
        const int row = rowmap(mt * 16 + lr, 1, j0);
        if (row >= 0) { Ah[mt][2] = ldA(Xhi, 128, row, kofs); Al[mt][2] = ldA(Xlo, 128, row, kofs); }
      }
    }
  }

  // ---- biases (per gate-thread j) ----
  const int jth = tid >> 6, bth = tid & 63;  // gate stage: 8 j x 64 b
  const float br   = p.bih[u][j0 + jth] + p.bhh[u][j0 + jth];
  const float bz   = p.bih[u][512 + j0 + jth] + p.bhh[u][512 + j0 + jth];
  const float bnih = p.bih[u][1024 + j0 + jth];
  const float bnhh = p.bhh[u][1024 + j0 + jth];

  int* own = p.flags + u * 64;
  int* sib = p.flags + (layer ? (u - 1) : (u + 1)) * 64;
  const int sBeg = layer ? 1 : 0;
  const int sEnd = layer ? TT : (TT - 1);

  for (int s = sBeg; s <= sEnd; ++s) {
    const int t = layer ? (s - 1) : s;

    float4v acc[2][4];
    #pragma unroll
    for (int mt = 0; mt < 2; ++mt)
      #pragma unroll
      for (int nt = 0; nt < 4; ++nt) acc[mt][nt] = (float4v)0.f;

    // ---- x contribution BEFORE the wait (independent of h; hides x fetch) ----
    if (!layer && wid < 4) {
      const int tx = dir ? (TT - 1 - t) : t;
      const int ko = wid * 32 + lq * 8;
      #pragma unroll
      for (int nt = 0; nt < 4; ++nt) {
        const int b = nt * 16 + lr;
        const float* xs = p.x + ((size_t)b * TT + tx) * DD + ko;
        short8v Bh, Bl;
        #pragma unroll
        for (int e = 0; e < 8; ++e) {
          const float xv = xs[e];
          const unsigned short hh = bf16_rne(xv);
          Bh[e] = (short)hh;
          Bl[e] = (short)bf16_rne(xv - bf16_f(hh));
        }
        #pragma unroll
        for (int mt = 0; mt < 2; ++mt) {
          acc[mt][nt] = MF(Ah[mt][2], Bh, acc[mt][nt]);
          acc[mt][nt] = MF(Al[mt][2], Bh, acc[mt][nt]);
          acc[mt][nt] = MF(Ah[mt][2], Bl, acc[mt][nt]);
        }
      }
    }

    // ---- wait for dependencies (wave 0 polls; relaxed loads, NO fences) ----
    if (wid == 0) {
      const int T1 = s - 1;
      const int T2 = layer ? (s - 1) : (s - 3);
      int iter = 0;
      while (true) {
        int f1 = __hip_atomic_load(own + lane, __ATOMIC_RELAXED, __HIP_MEMORY_SCOPE_AGENT);
        int f2 = __hip_atomic_load(sib + lane, __ATOMIC_RELAXED, __HIP_MEMORY_SCOPE_AGENT);
        if (__all(f1 >= T1 && f2 >= T2)) break;
        if (++iter > 1000000) {  // failsafe: terminate (results wrong but no hang)
          if (lane == 0)
            __hip_atomic_store(own + jt, 1 << 29, __ATOMIC_RELAXED, __HIP_MEMORY_SCOPE_AGENT);
          break;
        }
        __builtin_amdgcn_s_sleep(2);
      }
    }
    __syncthreads();

    // ---- h contributions (packed [k][64] planes) ----
    const unsigned* h0p = ws32 + O_H0_W + ((unsigned)dir * 4 + ((s - 1) & 3)) * 32768u;
    if (layer) {
      const int inp = (wid < 4);
      const unsigned* bbase = inp ? h0p
          : (ws32 + O_H1_W + ((unsigned)dir * 2 + (s & 1)) * 32768u);
      #pragma unroll
      for (int i = 0; i < 4; ++i) {
        const int kst_m = (wid * 4 + i) - (inp ? 0 : 16);
        const int ko = kst_m * 32 + lq * 8;
        #pragma unroll
        for (int nt = 0; nt < 4; ++nt) {
          const int b = nt * 16 + lr;
          short8v Bh, Bl;
          ldB(bbase, ko, b, Bh, Bl);
          #pragma unroll
          for (int mt = 0; mt < 2; ++mt) {
            acc[mt][nt] = MF(Ah[mt][i], Bh, acc[mt][nt]);
            acc[mt][nt] = MF(Al[mt][i], Bh, acc[mt][nt]);
            acc[mt][nt] = MF(Ah[mt][i], Bl, acc[mt][nt]);
          }
        }
      }
    } else {
      #pragma unroll
      for (int i = 0; i < 2; ++i) {
        const int ko = (wid * 2 + i) * 32 + lq * 8;
        #pragma unroll
        for (int nt = 0; nt < 4; ++nt) {
          const int b = nt * 16 + lr;
          short8v Bh, Bl;
          ldB(h0p, ko, b, Bh, Bl);
          #pragma unroll
          for (int mt = 0; mt < 2; ++mt) {
            acc[mt][nt] = MF(Ah[mt][i], Bh, acc[mt][nt]);
            acc[mt][nt] = MF(Al[mt][i], Bh, acc[mt][nt]);
            acc[mt][nt] = MF(Ah[mt][i], Bl, acc[mt][nt]);
          }
        }
      }
    }

    // ---- write partials to LDS (stride 68: 2-way = free) ----
    #pragma unroll
    for (int mt = 0; mt < 2; ++mt)
      #pragma unroll
      for (int nt = 0; nt < 4; ++nt)
        #pragma unroll
        for (int q = 0; q < 4; ++q)
          red[(wid * 32 + mt * 16 + lq * 4 + q) * 68 + nt * 16 + lr] = acc[mt][nt][q];
    __syncthreads();

    // ---- reduce + gates + packed coalesced store (thread: j=jth, b=bth) ----
    {
      float Sr = 0.f, Sz = 0.f, Sni = 0.f, Snh = 0.f;
      #pragma unroll
      for (int w = 0; w < 8; ++w) {
        Sr  += red[(w * 32 + jth) * 68 + bth];
        Sz  += red[(w * 32 + 8 + jth) * 68 + bth];
        Sni += red[(w * 32 + 16 + jth) * 68 + bth];
        Snh += red[(w * 32 + 24 + jth) * 68 + bth];
      }
      const float r = 1.f / (1.f + __expf(-(Sr + br)));
      const float z = 1.f / (1.f + __expf(-(Sz + bz)));
      const float n = tanhf(Sni + bnih + r * (Snh + bnhh));
      const unsigned idx = (unsigned)(j0 + jth) * 64u + (unsigned)bth;  // [k][b]
      const unsigned *hp; unsigned *hw;
      if (layer) {
        hp = ws32 + O_H1_W + ((unsigned)dir * 2 + (s & 1)) * 32768u;
        hw = ws32 + O_H1_W + ((unsigned)dir * 2 + ((s - 1) & 1)) * 32768u;
      } else {
        hp = ws32 + O_H0_W + ((unsigned)dir * 4 + ((s - 1) & 3)) * 32768u;
        hw = ws32 + O_H0_W + ((unsigned)dir * 4 + (s & 3)) * 32768u;
      }
      const unsigned pw0 = ald_w(hp + idx);
      const float hpv = bf16_f((unsigned short)(pw0 >> 16)) + bf16_f((unsigned short)(pw0 & 0xFFFFu));
      const float h = (1.f - z) * n + z * hpv;
      const unsigned short hh = bf16_rne(h);
      const unsigned short hl = bf16_rne(h - bf16_f(hh));
      ast_w(hw + idx, ((unsigned)hh << 16) | (unsigned)hl);
    }
    // __syncthreads drains vmcnt(0) => all h-stores at coherence point first
    __syncthreads();
    if (tid == 0)
      __hip_atomic_store(own + jt, s, __ATOMIC_RELAXED, __HIP_MEMORY_SCOPE_AGENT);
  }
}

// ---- prep: fp32 -> bf16 hi/lo split (weights) ----
__global__ void cvt_k(const float* __restrict__ src, unsigned short* __restrict__ hi,
                      unsigned short* __restrict__ lo, int n) {
  for (int i = blockIdx.x * blockDim.x + threadIdx.x; i < n; i += gridDim.x * blockDim.x) {
    const float w = src[i];
    const unsigned short h = bf16_rne(w);
    hi[i] = h;
    lo[i] = bf16_rne(w - bf16_f(h));
  }
}

__global__ void init_k(unsigned* ws32, int* flags) {
  for (unsigned i = blockIdx.x * blockDim.x + threadIdx.x; i < H_ZERO_W; i += gridDim.x * blockDim.x)
    ws32[O_H0_W + i] = 0u;
  const unsigned g = blockIdx.x * blockDim.x + threadIdx.x;
  if (g < 256) flags[g] = ((g >> 6) & 1) ? 0 : -1;  // L1 units start at 0, L0 at -1
}

// hidden = [h0_f | h1_f | h0_b | h1_b]; h0 final slot 3, h1 final slot 1
__global__ void gather_k(const unsigned* __restrict__ ws32, float* __restrict__ fc_in) {
  const int idx = blockIdx.x * blockDim.x + threadIdx.x;  // 64*2048
  const int b = idx >> 11, c = idx & 2047;
  const int seg = c >> 9, cc = c & 511;
  unsigned base;
  if (seg == 0)      base = O_H0_W + 3u * 32768u;
  else if (seg == 1) base = O_H1_W + 1u * 32768u;
  else if (seg == 2) base = O_H0_W + 7u * 32768u;
  else               base = O_H1_W + 3u * 32768u;
  const unsigned w = ws32[base + (unsigned)cc * 64u + (unsigned)b];
  fc_in[idx] = bf16_f((unsigned short)(w >> 16)) + bf16_f((unsigned short)(w & 0xFFFFu));
}

__global__ void fc_k(const float* __restrict__ in, const float* __restrict__ W,
                     const float* __restrict__ bias, float* __restrict__ out,
                     int K, int N, int leaky) {
  const int idx = blockIdx.x * blockDim.x + threadIdx.x;
  const int b = idx / N;
  const int n = idx - b * N;
  if (b >= BB) return;
  const float* ir = in + (size_t)b * K;
  const float* wr = W + (size_t)n * K;
  float acc = 0.f;
  for (int k = 0; k < K; k += 4) {
    const float4 a = *(const float4*)(ir + k);
    const float4 w = *(const float4*)(wr + k);
    acc += a.x * w.x + a.y * w.y + a.z * w.z + a.w * w.w;
  }
  acc += bias[n];
  if (leaky) acc = acc > 0.f ? acc : 0.01f * acc;
  out[idx] = acc;
}

extern "C" void kernel_launch(void* const* d_in, const int* in_sizes, int n_in,
                              void* d_out, int out_size, void* d_ws, size_t ws_size,
                              hipStream_t stream) {
  (void)in_sizes; (void)n_in; (void)out_size; (void)ws_size;

  PP P;
  P.x = (const float*)d_in[0];
  const float* Wih[4]; const float* Whh[4];
  for (int dir = 0; dir < 2; ++dir)
    for (int l = 0; l < 2; ++l) {
      const int base = 1 + (dir * 2 + l) * 4;
      const int u = dir * 2 + l;
      Wih[u] = (const float*)d_in[base + 0];
      Whh[u] = (const float*)d_in[base + 1];
      P.bih[u] = (const float*)d_in[base + 2];
      P.bhh[u] = (const float*)d_in[base + 3];
    }
  const float* Wfc0 = (const float*)d_in[17];
  const float* bfc0 = (const float*)d_in[18];
  const float* Wfc1 = (const float*)d_in[19];
  const float* bfc1 = (const float*)d_in[20];
  const float* Wfc2 = (const float*)d_in[21];
  const float* bfc2 = (const float*)d_in[22];

  unsigned short* wsu = (unsigned short*)d_ws;
  unsigned* ws32 = (unsigned*)d_ws;
  float* wsf = (float*)d_ws;
  int* flags = (int*)(ws32 + O_FLAGS_W);
  float* fc_in = wsf + O_FCIN_W;
  float* fc1o  = wsf + O_FC1O_W;
  float* fc2o  = wsf + O_FC2O_W;
  P.wsu = wsu; P.ws32 = ws32; P.flags = flags;

  hipFuncSetAttribute((const void*)gru_mfma,
                      hipFuncAttributeMaxDynamicSharedMemorySize, DYN_LDS);

  // ---- prep: weight split + h/flag init ----
  for (int u = 0; u < 4; ++u)
    hipLaunchKernelGGL(cvt_k, dim3(512), dim3(256), 0, stream,
                       Whh[u], wsu + O_WHH_HI + u * 786432u, wsu + O_WHH_LO + u * 786432u, 786432);
  for (int dir = 0; dir < 2; ++dir) {
    hipLaunchKernelGGL(cvt_k, dim3(512), dim3(256), 0, stream,
                       Wih[dir * 2 + 1], wsu + O_WIH1_HI + dir * 786432u, wsu + O_WIH1_LO + dir * 786432u, 786432);
    hipLaunchKernelGGL(cvt_k, dim3(256), dim3(256), 0, stream,
                       Wih[dir * 2 + 0], wsu + O_WIH0_HI + dir * 196608u, wsu + O_WIH0_LO + dir * 196608u, 196608);
  }
  hipLaunchKernelGGL(init_k, dim3(512), dim3(256), 0, stream, ws32, flags);

  // ---- persistent recurrence ----
  hipLaunchKernelGGL(gru_mfma, dim3(256), dim3(512), DYN_LDS, stream, P);

  // ---- FC head ----
  hipLaunchKernelGGL(gather_k, dim3(512), dim3(256), 0, stream, ws32, fc_in);
  hipLaunchKernelGGL(fc_k, dim3(256), dim3(256), 0, stream, fc_in, Wfc0, bfc0, fc1o, 2048, 1024, 1);
  hipLaunchKernelGGL(fc_k, dim3(128), dim3(256), 0, stream, fc1o, Wfc1, bfc1, fc2o, 1024, 512, 1);
  hipLaunchKernelGGL(fc_k, dim3(1), dim3(256), 0, stream, fc2o, Wfc2, bfc2, (float*)d_out, 512, 1, 0);
}

// Round 6
// 7593.779 us; speedup vs baseline: 12.6020x; 1.5487x over previous
//
#include <hip/hip_runtime.h>
#include <math.h>

typedef __attribute__((ext_vector_type(8))) short short8v;
typedef __attribute__((ext_vector_type(4))) float float4v;

#define BB 64
#define TT 1024
#define DD 128
#define HH 512

// ---- ushort (bf16) region: weights (element offsets) ----
#define O_WHH_HI  0u         // [4 units][1536][512]
#define O_WHH_LO  3145728u
#define O_WIH1_HI 6291456u   // [2 dir][1536][512]
#define O_WIH1_LO 7864320u
#define O_WIH0_HI 9437184u   // [2 dir][1536][128]
#define O_WIH0_LO 9830400u   // ends at 10223616 ushorts
// ---- 4-byte-word region (ws as unsigned*/float*), word offsets ----
#define O_H0_W    5111808u   // [2 dir][4 slot][512 k][64 b] packed hi|lo u32
#define O_H1_W    5373952u   // [2 dir][2 slot][512 k][64 b]
#define O_FLAGS_W 5505024u   // 256 ints: cnt[u][slot]=flags[u*32+slot]; gen[u]=flags[128+u*32]
#define O_FCIN_W  5505280u   // 131072 f
#define O_FC1O_W  5636352u   //  65536 f
#define O_FC2O_W  5701888u   //  32768 f
#define H_ZERO_W  393216u    // words to zero from O_H0_W

#define DYN_LDS   69632      // [8][32] x stride-68 f32 reduction buffer

struct PP {
  const float* x;
  const float* bih[4];
  const float* bhh[4];
  unsigned short* wsu;   // weight planes
  unsigned* ws32;        // packed h region
  int* flags;
};

__device__ __forceinline__ unsigned short bf16_rne(float f) {
  unsigned u = __builtin_bit_cast(unsigned, f);
  u += 0x7FFFu + ((u >> 16) & 1u);
  return (unsigned short)(u >> 16);
}
__device__ __forceinline__ float bf16_f(unsigned short h) {
  unsigned u = ((unsigned)h) << 16;
  return __builtin_bit_cast(float, u);
}
__device__ __forceinline__ float4v MF(short8v a, short8v b, float4v c) {
  return __builtin_amdgcn_mfma_f32_16x16x32_bf16(a, b, c, 0, 0, 0);
}
// agent-scope relaxed (coherence point, no fences)
__device__ __forceinline__ unsigned ald_w(const unsigned* p) {
  return __hip_atomic_load(p, __ATOMIC_RELAXED, __HIP_MEMORY_SCOPE_AGENT);
}
__device__ __forceinline__ void ast_w(unsigned* p, unsigned v) {
  __hip_atomic_store(p, v, __ATOMIC_RELAXED, __HIP_MEMORY_SCOPE_AGENT);
}
// load B fragment (8 k-elems for lane's batch col b) from packed [k][64] plane
__device__ __forceinline__ void ldB(const unsigned* base, int ko, int b,
                                    short8v& Bh, short8v& Bl) {
  #pragma unroll
  for (int e = 0; e < 8; ++e) {
    const unsigned w = ald_w(base + (unsigned)(ko + e) * 64u + (unsigned)b);
    Bh[e] = (short)(w >> 16);
    Bl[e] = (short)(w & 0xFFFFu);
  }
}

// row within stacked-[3*512] W for local row rl (0..31); -1 => zero frag
__device__ __forceinline__ int rowmap(int rl, int inp, int j0) {
  if (rl < 8)  return j0 + rl;
  if (rl < 16) return 512 + j0 + (rl - 8);
  if (rl < 24) return inp ? (1024 + j0 + rl - 16) : -1;
  return inp ? -1 : (1024 + j0 + rl - 24);
}
__device__ __forceinline__ short8v ldA(const unsigned short* W, int K, int row, int kofs) {
  return *(const short8v*)(W + (size_t)row * K + kofs);
}

// 256 blocks x 512 thr. u=bid>>6 (dir*2+layer), jt=bid&63 -> 8 j's.
// 8 waves split K; MFMA C[32 rows x 64 b]; rows: 0-7 r, 8-15 z, 16-23 n_ih, 24-31 n_hh.
// Sync: two-level barrier -> one generation word per unit (single-line polls).
__global__ __launch_bounds__(512) void gru_mfma(PP p) {
  extern __shared__ float red[];  // [8][32] stride 68
  const int bid = blockIdx.x;
  const int u = bid >> 6, dir = u >> 1, layer = u & 1;
  const int jt = bid & 63, j0 = jt * 8;
  const int tid = threadIdx.x, wid = tid >> 6, lane = tid & 63;
  const int lr = lane & 15, lq = lane >> 4;
  unsigned short* wsu = p.wsu;
  unsigned* ws32 = p.ws32;

  // ---- preload A fragments (weights) into VGPRs (normal cached loads) ----
  short8v Ah[2][4], Al[2][4];
  #pragma unroll
  for (int mt = 0; mt < 2; ++mt)
    #pragma unroll
    for (int i = 0; i < 4; ++i) { Ah[mt][i] = (short8v)0; Al[mt][i] = (short8v)0; }

  if (layer) {
    const int inp = (wid < 4);  // waves 0-3: input part (Wih_l1), 4-7: hidden (Whh)
    const unsigned short* Whi = inp ? (wsu + O_WIH1_HI + dir * 786432u)
                                    : (wsu + O_WHH_HI + (unsigned)u * 786432u);
    const unsigned short* Wlo = inp ? (wsu + O_WIH1_LO + dir * 786432u)
                                    : (wsu + O_WHH_LO + (unsigned)u * 786432u);
    #pragma unroll
    for (int i = 0; i < 4; ++i) {
      const int kst_m = (wid * 4 + i) - (inp ? 0 : 16);
      const int kofs = kst_m * 32 + lq * 8;
      #pragma unroll
      for (int mt = 0; mt < 2; ++mt) {
        const int row = rowmap(mt * 16 + lr, inp, j0);
        if (row >= 0) { Ah[mt][i] = ldA(Whi, 512, row, kofs); Al[mt][i] = ldA(Wlo, 512, row, kofs); }
      }
    }
  } else {
    const unsigned short* Whi = wsu + O_WHH_HI + (unsigned)u * 786432u;
    const unsigned short* Wlo = wsu + O_WHH_LO + (unsigned)u * 786432u;
    #pragma unroll
    for (int i = 0; i < 2; ++i) {
      const int kofs = (wid * 2 + i) * 32 + lq * 8;
      #pragma unroll
      for (int mt = 0; mt < 2; ++mt) {
        const int row = rowmap(mt * 16 + lr, 0, j0);
        if (row >= 0) { Ah[mt][i] = ldA(Whi, 512, row, kofs); Al[mt][i] = ldA(Wlo, 512, row, kofs); }
      }
    }
    if (wid < 4) {  // x part: K=128, wave wid owns kst wid
      const unsigned short* Xhi = wsu + O_WIH0_HI + dir * 196608u;
      const unsigned short* Xlo = wsu + O_WIH0_LO + dir * 196608u;
      const int kofs = wid * 32 + lq * 8;
      #pragma unroll
      for (int mt = 0; mt < 2; ++mt) {
        const int row = rowmap(mt * 16 + lr, 1, j0);
        if (row >= 0) { Ah[mt][2] = ldA(Xhi, 128, row, kofs); Al[mt][2] = ldA(Xlo, 128, row, kofs); }
      }
    }
  }

  // ---- biases (per gate-thread j) ----
  const int jth = tid >> 6, bth = tid & 63;  // gate stage: 8 j x 64 b
  const float br   = p.bih[u][j0 + jth] + p.bhh[u][j0 + jth];
  const float bz   = p.bih[u][512 + j0 + jth] + p.bhh[u][512 + j0 + jth];
  const float bnih = p.bih[u][1024 + j0 + jth];
  const float bnhh = p.bhh[u][1024 + j0 + jth];

  const int usib = layer ? (u - 1) : (u + 1);
  int* cntU   = p.flags + u * 32;            // 4 rotating slots
  int* genOwn = p.flags + 128 + u * 32;
  int* genSib = p.flags + 128 + usib * 32;
  const int sBeg = layer ? 1 : 0;
  const int sEnd = layer ? TT : (TT - 1);

  for (int s = sBeg; s <= sEnd; ++s) {
    const int t = layer ? (s - 1) : s;

    float4v acc[2][4];
    #pragma unroll
    for (int mt = 0; mt < 2; ++mt)
      #pragma unroll
      for (int nt = 0; nt < 4; ++nt) acc[mt][nt] = (float4v)0.f;

    // ---- x contribution BEFORE the wait (independent of h; hides x fetch) ----
    if (!layer && wid < 4) {
      const int tx = dir ? (TT - 1 - t) : t;
      const int ko = wid * 32 + lq * 8;
      #pragma unroll
      for (int nt = 0; nt < 4; ++nt) {
        const int b = nt * 16 + lr;
        const float* xs = p.x + ((size_t)b * TT + tx) * DD + ko;
        short8v Bh, Bl;
        #pragma unroll
        for (int e = 0; e < 8; ++e) {
          const float xv = xs[e];
          const unsigned short hh = bf16_rne(xv);
          Bh[e] = (short)hh;
          Bl[e] = (short)bf16_rne(xv - bf16_f(hh));
        }
        #pragma unroll
        for (int mt = 0; mt < 2; ++mt) {
          acc[mt][nt] = MF(Ah[mt][2], Bh, acc[mt][nt]);
          acc[mt][nt] = MF(Al[mt][2], Bh, acc[mt][nt]);
          acc[mt][nt] = MF(Ah[mt][2], Bl, acc[mt][nt]);
        }
      }
    }

    // ---- wait: poll two generation words (uniform, relaxed, NO fences) ----
    if (wid == 0) {
      const int T1 = s - 1;
      const int T2 = layer ? (s - 1) : (s - 3);
      int iter = 0;
      while (true) {
        const int g1 = __hip_atomic_load(genOwn, __ATOMIC_RELAXED, __HIP_MEMORY_SCOPE_AGENT);
        const int g2 = __hip_atomic_load(genSib, __ATOMIC_RELAXED, __HIP_MEMORY_SCOPE_AGENT);
        if (g1 >= T1 && g2 >= T2) break;
        if (++iter > 2000000) {  // failsafe: no hang; release others and proceed
          if (lane == 0)
            __hip_atomic_store(genOwn, 1 << 29, __ATOMIC_RELAXED, __HIP_MEMORY_SCOPE_AGENT);
          break;
        }
        __builtin_amdgcn_s_sleep(2);
      }
    }
    __syncthreads();

    // ---- h contributions (packed [k][64] planes) ----
    const unsigned* h0p = ws32 + O_H0_W + ((unsigned)dir * 4 + ((s - 1) & 3)) * 32768u;
    if (layer) {
      const int inp = (wid < 4);
      const unsigned* bbase = inp ? h0p
          : (ws32 + O_H1_W + ((unsigned)dir * 2 + (s & 1)) * 32768u);
      #pragma unroll
      for (int i = 0; i < 4; ++i) {
        const int kst_m = (wid * 4 + i) - (inp ? 0 : 16);
        const int ko = kst_m * 32 + lq * 8;
        #pragma unroll
        for (int nt = 0; nt < 4; ++nt) {
          const int b = nt * 16 + lr;
          short8v Bh, Bl;
          ldB(bbase, ko, b, Bh, Bl);
          #pragma unroll
          for (int mt = 0; mt < 2; ++mt) {
            acc[mt][nt] = MF(Ah[mt][i], Bh, acc[mt][nt]);
            acc[mt][nt] = MF(Al[mt][i], Bh, acc[mt][nt]);
            acc[mt][nt] = MF(Ah[mt][i], Bl, acc[mt][nt]);
          }
        }
      }
    } else {
      #pragma unroll
      for (int i = 0; i < 2; ++i) {
        const int ko = (wid * 2 + i) * 32 + lq * 8;
        #pragma unroll
        for (int nt = 0; nt < 4; ++nt) {
          const int b = nt * 16 + lr;
          short8v Bh, Bl;
          ldB(h0p, ko, b, Bh, Bl);
          #pragma unroll
          for (int mt = 0; mt < 2; ++mt) {
            acc[mt][nt] = MF(Ah[mt][i], Bh, acc[mt][nt]);
            acc[mt][nt] = MF(Al[mt][i], Bh, acc[mt][nt]);
            acc[mt][nt] = MF(Ah[mt][i], Bl, acc[mt][nt]);
          }
        }
      }
    }

    // ---- write partials to LDS (stride 68: 2-way = free) ----
    #pragma unroll
    for (int mt = 0; mt < 2; ++mt)
      #pragma unroll
      for (int nt = 0; nt < 4; ++nt)
        #pragma unroll
        for (int q = 0; q < 4; ++q)
          red[(wid * 32 + mt * 16 + lq * 4 + q) * 68 + nt * 16 + lr] = acc[mt][nt][q];
    __syncthreads();

    // ---- reduce + gates + packed coalesced store (thread: j=jth, b=bth) ----
    {
      float Sr = 0.f, Sz = 0.f, Sni = 0.f, Snh = 0.f;
      #pragma unroll
      for (int w = 0; w < 8; ++w) {
        Sr  += red[(w * 32 + jth) * 68 + bth];
        Sz  += red[(w * 32 + 8 + jth) * 68 + bth];
        Sni += red[(w * 32 + 16 + jth) * 68 + bth];
        Snh += red[(w * 32 + 24 + jth) * 68 + bth];
      }
      const float r = 1.f / (1.f + __expf(-(Sr + br)));
      const float z = 1.f / (1.f + __expf(-(Sz + bz)));
      const float n = tanhf(Sni + bnih + r * (Snh + bnhh));
      const unsigned idx = (unsigned)(j0 + jth) * 64u + (unsigned)bth;  // [k][b]
      const unsigned *hp; unsigned *hw;
      if (layer) {
        hp = ws32 + O_H1_W + ((unsigned)dir * 2 + (s & 1)) * 32768u;
        hw = ws32 + O_H1_W + ((unsigned)dir * 2 + ((s - 1) & 1)) * 32768u;
      } else {
        hp = ws32 + O_H0_W + ((unsigned)dir * 4 + ((s - 1) & 3)) * 32768u;
        hw = ws32 + O_H0_W + ((unsigned)dir * 4 + (s & 3)) * 32768u;
      }
      const unsigned pw0 = ald_w(hp + idx);
      const float hpv = bf16_f((unsigned short)(pw0 >> 16)) + bf16_f((unsigned short)(pw0 & 0xFFFFu));
      const float h = (1.f - z) * n + z * hpv;
      const unsigned short hh = bf16_rne(h);
      const unsigned short hl = bf16_rne(h - bf16_f(hh));
      ast_w(hw + idx, ((unsigned)hh << 16) | (unsigned)hl);
    }
    // __syncthreads drains vmcnt(0) => all h-stores at coherence point first
    __syncthreads();
    if (tid == 0) {
      const int old = __hip_atomic_fetch_add(cntU + (s & 3), 1, __ATOMIC_RELAXED,
                                             __HIP_MEMORY_SCOPE_AGENT);
      if (old == 63) {  // last arrival: recycle slot s+2, then publish generation s
        __hip_atomic_store(cntU + ((s + 2) & 3), 0, __ATOMIC_RELAXED, __HIP_MEMORY_SCOPE_AGENT);
        __hip_atomic_store(genOwn, s, __ATOMIC_RELAXED, __HIP_MEMORY_SCOPE_AGENT);
      }
    }
  }
}

// ---- prep: fp32 -> bf16 hi/lo split (weights) ----
__global__ void cvt_k(const float* __restrict__ src, unsigned short* __restrict__ hi,
                      unsigned short* __restrict__ lo, int n) {
  for (int i = blockIdx.x * blockDim.x + threadIdx.x; i < n; i += gridDim.x * blockDim.x) {
    const float w = src[i];
    const unsigned short h = bf16_rne(w);
    hi[i] = h;
    lo[i] = bf16_rne(w - bf16_f(h));
  }
}

__global__ void init_k(unsigned* ws32, int* flags) {
  for (unsigned i = blockIdx.x * blockDim.x + threadIdx.x; i < H_ZERO_W; i += gridDim.x * blockDim.x)
    ws32[O_H0_W + i] = 0u;
  const unsigned g = blockIdx.x * blockDim.x + threadIdx.x;
  if (g < 256) {
    int v = 0;
    if (g >= 128 && ((g - 128) & 31) == 0) {
      const unsigned uu = (g - 128) >> 5;     // gen[u]: L1 units (u odd) start 0, L0 -1
      v = (uu & 1) ? 0 : -1;
    }
    flags[g] = v;
  }
}

// hidden = [h0_f | h1_f | h0_b | h1_b]; h0 final slot 3, h1 final slot 1
__global__ void gather_k(const unsigned* __restrict__ ws32, float* __restrict__ fc_in) {
  const int idx = blockIdx.x * blockDim.x + threadIdx.x;  // 64*2048
  const int b = idx >> 11, c = idx & 2047;
  const int seg = c >> 9, cc = c & 511;
  unsigned base;
  if (seg == 0)      base = O_H0_W + 3u * 32768u;
  else if (seg == 1) base = O_H1_W + 1u * 32768u;
  else if (seg == 2) base = O_H0_W + 7u * 32768u;
  else               base = O_H1_W + 3u * 32768u;
  const unsigned w = ws32[base + (unsigned)cc * 64u + (unsigned)b];
  fc_in[idx] = bf16_f((unsigned short)(w >> 16)) + bf16_f((unsigned short)(w & 0xFFFFu));
}

__global__ void fc_k(const float* __restrict__ in, const float* __restrict__ W,
                     const float* __restrict__ bias, float* __restrict__ out,
                     int K, int N, int leaky) {
  const int idx = blockIdx.x * blockDim.x + threadIdx.x;
  const int b = idx / N;
  const int n = idx - b * N;
  if (b >= BB) return;
  const float* ir = in + (size_t)b * K;
  const float* wr = W + (size_t)n * K;
  float acc = 0.f;
  for (int k = 0; k < K; k += 4) {
    const float4 a = *(const float4*)(ir + k);
    const float4 w = *(const float4*)(wr + k);
    acc += a.x * w.x + a.y * w.y + a.z * w.z + a.w * w.w;
  }
  acc += bias[n];
  if (leaky) acc = acc > 0.f ? acc : 0.01f * acc;
  out[idx] = acc;
}

extern "C" void kernel_launch(void* const* d_in, const int* in_sizes, int n_in,
                              void* d_out, int out_size, void* d_ws, size_t ws_size,
                              hipStream_t stream) {
  (void)in_sizes; (void)n_in; (void)out_size; (void)ws_size;

  PP P;
  P.x = (const float*)d_in[0];
  const float* Wih[4]; const float* Whh[4];
  for (int dir = 0; dir < 2; ++dir)
    for (int l = 0; l < 2; ++l) {
      const int base = 1 + (dir * 2 + l) * 4;
      const int u = dir * 2 + l;
      Wih[u] = (const float*)d_in[base + 0];
      Whh[u] = (const float*)d_in[base + 1];
      P.bih[u] = (const float*)d_in[base + 2];
      P.bhh[u] = (const float*)d_in[base + 3];
    }
  const float* Wfc0 = (const float*)d_in[17];
  const float* bfc0 = (const float*)d_in[18];
  const float* Wfc1 = (const float*)d_in[19];
  const float* bfc1 = (const float*)d_in[20];
  const float* Wfc2 = (const float*)d_in[21];
  const float* bfc2 = (const float*)d_in[22];

  unsigned short* wsu = (unsigned short*)d_ws;
  unsigned* ws32 = (unsigned*)d_ws;
  float* wsf = (float*)d_ws;
  int* flags = (int*)(ws32 + O_FLAGS_W);
  float* fc_in = wsf + O_FCIN_W;
  float* fc1o  = wsf + O_FC1O_W;
  float* fc2o  = wsf + O_FC2O_W;
  P.wsu = wsu; P.ws32 = ws32; P.flags = flags;

  hipFuncSetAttribute((const void*)gru_mfma,
                      hipFuncAttributeMaxDynamicSharedMemorySize, DYN_LDS);

  // ---- prep: weight split + h/flag init ----
  for (int u = 0; u < 4; ++u)
    hipLaunchKernelGGL(cvt_k, dim3(512), dim3(256), 0, stream,
                       Whh[u], wsu + O_WHH_HI + u * 786432u, wsu + O_WHH_LO + u * 786432u, 786432);
  for (int dir = 0; dir < 2; ++dir) {
    hipLaunchKernelGGL(cvt_k, dim3(512), dim3(256), 0, stream,
                       Wih[dir * 2 + 1], wsu + O_WIH1_HI + dir * 786432u, wsu + O_WIH1_LO + dir * 786432u, 786432);
    hipLaunchKernelGGL(cvt_k, dim3(256), dim3(256), 0, stream,
                       Wih[dir * 2 + 0], wsu + O_WIH0_HI + dir * 196608u, wsu + O_WIH0_LO + dir * 196608u, 196608);
  }
  hipLaunchKernelGGL(init_k, dim3(512), dim3(256), 0, stream, ws32, flags);

  // ---- persistent recurrence ----
  hipLaunchKernelGGL(gru_mfma, dim3(256), dim3(512), DYN_LDS, stream, P);

  // ---- FC head ----
  hipLaunchKernelGGL(gather_k, dim3(512), dim3(256), 0, stream, ws32, fc_in);
  hipLaunchKernelGGL(fc_k, dim3(256), dim3(256), 0, stream, fc_in, Wfc0, bfc0, fc1o, 2048, 1024, 1);
  hipLaunchKernelGGL(fc_k, dim3(128), dim3(256), 0, stream, fc1o, Wfc1, bfc1, fc2o, 1024, 512, 1);
  hipLaunchKernelGGL(fc_k, dim3(1), dim3(256), 0, stream, fc2o, Wfc2, bfc2, (float*)d_out, 512, 1, 0);
}